// Round 4
// baseline (150.779 us; speedup 1.0000x reference)
//
#include <hip/hip_runtime.h>
#include <math.h>

// Problem constants
#define KC 1024       // num codes
#define DD 256        // embedding dim
#define NROWS 32768   // 32 * 32 * 32 (B*H*W)
#define NELEM 8388608 // NROWS * DD

typedef _Float16 f16;
typedef __attribute__((ext_vector_type(8))) _Float16 f16x8;
typedef __attribute__((ext_vector_type(16))) float f32x16;

// ---------------------------------------------------------------------------
// prep: zero counts/loss/done + c_sq (exact fp32) + emb -> fp16 swizzled
// grid 256 x 256.  emb_h layout: [kg 32][code 1024][8]
// ---------------------------------------------------------------------------
__global__ void vq_prep_kernel(const float* __restrict__ emb, f16* __restrict__ emb_h,
                               float* __restrict__ c_sq, int* __restrict__ counts,
                               float* __restrict__ loss_acc, unsigned* __restrict__ done) {
    const int tid = threadIdx.x;
    const int gt = blockIdx.x * 256 + tid;
    if (gt < KC) counts[gt] = 0;
    if (gt == 0) { *loss_acc = 0.0f; *done = 0u; }
    // c_sq: 4 codes/block, one per wave
    {
        int k = blockIdx.x * 4 + (tid >> 6);
        int lane = tid & 63;
        float4 v = *(const float4*)(emb + (size_t)k * DD + lane * 4);
        float s = v.x * v.x + v.y * v.y + v.z * v.z + v.w * v.w;
        #pragma unroll
        for (int off = 32; off > 0; off >>= 1) s += __shfl_down(s, off);
        if (lane == 0) c_sq[k] = s;
    }
    // embh: blocks 0..127 cover 32768 granules of 8 halfs
    if (gt < 32768) {
        int code = gt & 1023;
        int kg = gt >> 10;
        const float* p = emb + (size_t)code * DD + kg * 8;
        float4 v0 = *(const float4*)p;
        float4 v1 = *(const float4*)(p + 4);
        f16x8 h;
        h[0] = (f16)v0.x; h[1] = (f16)v0.y; h[2] = (f16)v0.z; h[3] = (f16)v0.w;
        h[4] = (f16)v1.x; h[5] = (f16)v1.y; h[6] = (f16)v1.z; h[7] = (f16)v1.w;
        *(f16x8*)(emb_h + (size_t)gt * 8) = h;
    }
}

// ---------------------------------------------------------------------------
// Fused: dist (MFMA) + argmin + loss-from-score + gather + transpose-write
// + last-block finalize.  Block = 64 rows x 512 threads (8 waves); grid 512
// -> 2 blocks/CU, 16 waves/CU.  Wave w owns codes [w*128, w*128+128).
// LDS: smem_raw = union(z_s fp16 32KB, Qh fp32 64x260 = 66.6KB) + ~8KB misc.
// Loss trick: sum_row (q - z)^2 = score_min + ||z||^2  (score = c2 - 2 z.e).
// ---------------------------------------------------------------------------
__device__ __forceinline__ void upd(float& bv, int& bi, float v, int i) {
    if (v < bv) { bv = v; bi = i; }
}

__global__ __launch_bounds__(512, 4)
void vq_main_kernel(const float* __restrict__ z, const float* __restrict__ emb,
                    const f16* __restrict__ emb_h, const float* __restrict__ c_sq,
                    int* __restrict__ counts, float* __restrict__ loss_acc,
                    unsigned* __restrict__ done, float* __restrict__ out,
                    float* __restrict__ out_tail) {
    __shared__ __align__(16) char smem_raw[66560]; // z_s (A/B) then Qh (C)
    __shared__ float bl_v[8][64];
    __shared__ int   bl_i[8][64];
    __shared__ float zsq_part[8][64];
    __shared__ int   idx_s[64];
    __shared__ float wsum[8];
    __shared__ int   last_flag;

    f16* z_s = (f16*)smem_raw;          // [kg 32][row 64][8]
    float* Qh = (float*)smem_raw;       // [row 64][260]

    const int tid = threadIdx.x;
    const int n0 = blockIdx.x * 64;
    const int b = n0 >> 10;
    const int hw0 = n0 & 1023;

    // ---- Phase A: stage z tile fp16 + per-row ||z||^2 partials ----
    {
        const int r = tid & 63;
        const int kq = tid >> 6;  // 0..7
        const float* zp = z + (size_t)b * (DD * 1024) + hw0 + r;
        float sq = 0.f;
        #pragma unroll
        for (int it = 0; it < 4; ++it) {
            int kg = kq * 4 + it;
            f16x8 hv;
            #pragma unroll
            for (int j = 0; j < 8; ++j) {
                float v = zp[(size_t)(kg * 8 + j) * 1024];
                sq += v * v;
                hv[j] = (f16)v;
            }
            *(f16x8*)&z_s[(kg * 64 + r) * 8] = hv;
        }
        zsq_part[kq][r] = sq;
    }
    __syncthreads();

    const int m = tid & 31;        // code-lane within 32-tile
    const int h = (tid >> 5) & 1;  // k-half
    const int w = tid >> 6;        // wave id 0..7

    float bv[32];
    int bi[32];
    #pragma unroll
    for (int s = 0; s < 32; ++s) { bv[s] = 3.0e38f; bi[s] = 0; }

    // ---- Phase B: MFMA + running argmin (wave-local 128 codes) ----
    for (int c = 0; c < 2; ++c) {
        const int cb = w * 128 + c * 64;
        const f16* ebp = emb_h + (size_t)h * 8192 + (size_t)(cb + m) * 8;

        f32x16 acc00, acc01, acc10, acc11;
        #pragma unroll
        for (int i = 0; i < 16; ++i) { acc00[i] = 0.f; acc01[i] = 0.f; acc10[i] = 0.f; acc11[i] = 0.f; }

        #pragma unroll 4
        for (int ks = 0; ks < 16; ++ks) {
            const f16* za = z_s + (2 * ks + h) * 512 + m * 8;
            f16x8 a0 = *(const f16x8*)(za);          // rows m
            f16x8 a1 = *(const f16x8*)(za + 256);    // rows m+32
            f16x8 b0 = *(const f16x8*)(ebp + (size_t)ks * 16384);
            f16x8 b1 = *(const f16x8*)(ebp + (size_t)ks * 16384 + 256);
            acc00 = __builtin_amdgcn_mfma_f32_32x32x16_f16(a0, b0, acc00, 0, 0, 0);
            acc01 = __builtin_amdgcn_mfma_f32_32x32x16_f16(a0, b1, acc01, 0, 0, 0);
            acc10 = __builtin_amdgcn_mfma_f32_32x32x16_f16(a1, b0, acc10, 0, 0, 0);
            acc11 = __builtin_amdgcn_mfma_f32_32x32x16_f16(a1, b1, acc11, 0, 0, 0);
        }

        const int code0 = cb + m;
        const int code1 = cb + 32 + m;
        const float cs0 = c_sq[code0];
        const float cs1 = c_sq[code1];
        #pragma unroll
        for (int reg = 0; reg < 16; ++reg) {
            upd(bv[reg], bi[reg], fmaf(-2.f, acc00[reg], cs0), code0);
            upd(bv[reg], bi[reg], fmaf(-2.f, acc01[reg], cs1), code1);
            upd(bv[16 + reg], bi[16 + reg], fmaf(-2.f, acc10[reg], cs0), code0);
            upd(bv[16 + reg], bi[16 + reg], fmaf(-2.f, acc11[reg], cs1), code1);
        }
    }

    // butterfly argmin across 32 lanes of each half
    #pragma unroll
    for (int s = 0; s < 32; ++s) {
        float v = bv[s];
        int i = bi[s];
        #pragma unroll
        for (int d = 16; d >= 1; d >>= 1) {
            float ov = __shfl_xor(v, d);
            int oi = __shfl_xor(i, d);
            if (ov < v || (ov == v && oi < i)) { v = ov; i = oi; }
        }
        bv[s] = v; bi[s] = i;
    }
    if (m == 0) {
        #pragma unroll
        for (int s = 0; s < 32; ++s) {
            int rt = s >> 4, reg = s & 15;
            int row = rt * 32 + (reg & 3) + 8 * (reg >> 2) + 4 * h;
            bl_v[w][row] = bv[s];
            bl_i[w][row] = bi[s];
        }
    }
    __syncthreads();

    // combine 8 waves (ascending code ranges) -> idx, hist, loss-from-score
    if (tid < 64) {
        float v = bl_v[0][tid];
        int i = bl_i[0][tid];
        #pragma unroll
        for (int w2 = 1; w2 < 8; ++w2) {
            float ov = bl_v[w2][tid];
            int oi = bl_i[w2][tid];
            if (ov < v || (ov == v && oi < i)) { v = ov; i = oi; }
        }
        idx_s[tid] = i;
        atomicAdd(&counts[i], 1);
        float zq = 0.f;
        #pragma unroll
        for (int p = 0; p < 8; ++p) zq += zsq_part[p][tid];
        float lr = v + zq;   // = sum_c (q-z)^2 for this row
        #pragma unroll
        for (int off = 32; off > 0; off >>= 1) lr += __shfl_down(lr, off);
        if (tid == 0) atomicAdd(loss_acc, lr);
    }
    __syncthreads();

    // ---- Phase C1: Qh[r][c] = emb[idx[r]][c] fp32, stride 260 (bank-clean) ----
    {
        int r = tid & 63;
        int part = tid >> 6;  // 0..7 -> 32 channels each
        const float* ep = emb + (size_t)idx_s[r] * DD + part * 32;
        float* qrow = Qh + r * 260 + part * 32;
        #pragma unroll
        for (int g = 0; g < 8; ++g)
            *(float4*)(qrow + g * 4) = *(const float4*)(ep + g * 4);
    }
    __syncthreads();

    // ---- Phase C2: coalesced channel-major writes ----
    {
        int r = tid & 63;
        const float* qr = Qh + r * 260;
        const size_t base = (size_t)b * (DD * 1024) + hw0 + r;
        #pragma unroll
        for (int g = 0; g < 8; ++g) {
            int c0 = w * 32 + g * 4;
            float4 v = *(const float4*)(qr + c0);
            out[base + (size_t)c0 * 1024] = v.x;
            out[base + (size_t)(c0 + 1) * 1024] = v.y;
            out[base + (size_t)(c0 + 2) * 1024] = v.z;
            out[base + (size_t)(c0 + 3) * 1024] = v.w;
        }
    }

    // ---- last-block finalize: loss scalar + perplexity ----
    __syncthreads();
    if (tid == 0) {
        __threadfence();
        last_flag = (atomicAdd(done, 1u) == 511u) ? 1 : 0;
    }
    __syncthreads();
    if (last_flag) {
        __threadfence();
        float s = 0.f;
        for (int k = tid; k < KC; k += 512) {
            int cnt = atomicAdd(&counts[k], 0);  // coherent device-scope read
            float p = (float)cnt * (1.0f / (float)NROWS);
            s += p * logf(p + 1e-10f);
        }
        #pragma unroll
        for (int off = 32; off > 0; off >>= 1) s += __shfl_down(s, off);
        if ((tid & 63) == 0) wsum[w] = s;
        __syncthreads();
        if (tid == 0) {
            float ent = 0.f;
            #pragma unroll
            for (int p = 0; p < 8; ++p) ent += wsum[p];
            float ls = atomicAdd(loss_acc, 0.0f);  // coherent read
            out_tail[0] = 1.25f * ls * (1.0f / (float)NELEM);
            out_tail[1] = expf(-ent);
        }
    }
}

// ---------------------------------------------------------------------------
extern "C" void kernel_launch(void* const* d_in, const int* in_sizes, int n_in,
                              void* d_out, int out_size, void* d_ws, size_t ws_size,
                              hipStream_t stream) {
    const float* z = (const float*)d_in[0];    // (32,256,32,32)
    const float* emb = (const float*)d_in[1];  // (1024,256)
    float* out = (float*)d_out;                // 8388608 + 2

    // ws layout (bytes): emb_h [0,524288) | c_sq | counts | loss | done
    char* wsb = (char*)d_ws;
    f16* emb_h = (f16*)wsb;
    float* c_sq = (float*)(wsb + 524288);
    int* counts = (int*)(wsb + 528384);
    float* loss_acc = (float*)(wsb + 532480);
    unsigned* done = (unsigned*)(wsb + 532484);

    hipLaunchKernelGGL(vq_prep_kernel, dim3(256), dim3(256), 0, stream,
                       emb, emb_h, c_sq, counts, loss_acc, done);
    hipLaunchKernelGGL(vq_main_kernel, dim3(512), dim3(512), 0, stream,
                       z, emb, emb_h, c_sq, counts, loss_acc, done, out, out + NELEM);
}

// Round 5
// 132.538 us; speedup vs baseline: 1.1376x; 1.1376x over previous
//
#include <hip/hip_runtime.h>
#include <math.h>

// Problem constants
#define KC 1024       // num codes
#define DD 256        // embedding dim
#define NROWS 32768   // 32 * 32 * 32 (B*H*W)
#define NELEM 8388608 // NROWS * DD

typedef _Float16 f16;
typedef __attribute__((ext_vector_type(8))) _Float16 f16x8;
typedef __attribute__((ext_vector_type(16))) float f32x16;

#define KEY_SCALE 2097152.0f   // 2^21; |score| <= ~0.63 -> |ikey| < 2^21
#define KEY_INV   (1.0f / 2097152.0f)

// ---------------------------------------------------------------------------
// prep: zero counts/loss/done + c_sq (exact fp32) + emb -> fp16 swizzled
// grid 256 x 256.  emb_h layout: [kg 32][code 1024][8]
// ---------------------------------------------------------------------------
__global__ void vq_prep_kernel(const float* __restrict__ emb, f16* __restrict__ emb_h,
                               float* __restrict__ c_sq, int* __restrict__ counts,
                               float* __restrict__ loss_acc, unsigned* __restrict__ done) {
    const int tid = threadIdx.x;
    const int gt = blockIdx.x * 256 + tid;
    if (gt < KC) counts[gt] = 0;
    if (gt == 0) { *loss_acc = 0.0f; *done = 0u; }
    {
        int k = blockIdx.x * 4 + (tid >> 6);
        int lane = tid & 63;
        float4 v = *(const float4*)(emb + (size_t)k * DD + lane * 4);
        float s = v.x * v.x + v.y * v.y + v.z * v.z + v.w * v.w;
        #pragma unroll
        for (int off = 32; off > 0; off >>= 1) s += __shfl_down(s, off);
        if (lane == 0) c_sq[k] = s;
    }
    if (gt < 32768) {
        int code = gt & 1023;
        int kg = gt >> 10;
        const float* p = emb + (size_t)code * DD + kg * 8;
        float4 v0 = *(const float4*)p;
        float4 v1 = *(const float4*)(p + 4);
        f16x8 h;
        h[0] = (f16)v0.x; h[1] = (f16)v0.y; h[2] = (f16)v0.z; h[3] = (f16)v0.w;
        h[4] = (f16)v1.x; h[5] = (f16)v1.y; h[6] = (f16)v1.z; h[7] = (f16)v1.w;
        *(f16x8*)(emb_h + (size_t)gt * 8) = h;
    }
}

// ---------------------------------------------------------------------------
// Fused main: dist (MFMA) + packed-int argmin + loss-from-score + gather +
// transpose-write + last-block finalize.
// Block = 64 rows x 512 threads (8 waves), grid 512 -> 2 blocks/CU,
// 16 waves/CU at <=128 regs (32 acc + 32 keys + frags + addr ~ 91).
// Wave w owns codes [w*128,(w+1)*128) as 4 chunks of 32 codes; per chunk
// 2 row-tile accumulators (rows m, m+32).
// argmin key = trunc(score*2^21)*1024 + code  (monotone, first-min ties).
// loss per row: sum_c (q-z)^2 = score_min + ||z||^2.
// ---------------------------------------------------------------------------
__global__ __launch_bounds__(512, 4)
void vq_main_kernel(const float* __restrict__ z, const float* __restrict__ emb,
                    const f16* __restrict__ emb_h, const float* __restrict__ c_sq,
                    int* __restrict__ counts, float* __restrict__ loss_acc,
                    unsigned* __restrict__ done, float* __restrict__ out,
                    float* __restrict__ out_tail) {
    __shared__ __align__(16) char smem_raw[66560]; // z_s (A/B) then Qh (C)
    __shared__ int   bl_key[8][64];
    __shared__ float zsq_part[8][64];
    __shared__ int   idx_s[64];
    __shared__ float wsum[8];
    __shared__ int   last_flag;

    f16* z_s = (f16*)smem_raw;      // [kg 32][row 64][8]
    float* Qh = (float*)smem_raw;   // [row 64][260]

    const int tid = threadIdx.x;
    const int n0 = blockIdx.x * 64;
    const int b = n0 >> 10;
    const int hw0 = n0 & 1023;

    // ---- Phase A: stage z tile fp16 + per-row ||z||^2 partials ----
    {
        const int r = tid & 63;
        const int kq = tid >> 6;  // 0..7
        const float* zp = z + (size_t)b * (DD * 1024) + hw0 + r;
        float sq = 0.f;
        #pragma unroll
        for (int it = 0; it < 4; ++it) {
            int kg = kq * 4 + it;
            f16x8 hv;
            #pragma unroll
            for (int j = 0; j < 8; ++j) {
                float v = zp[(size_t)(kg * 8 + j) * 1024];
                sq += v * v;
                hv[j] = (f16)v;
            }
            *(f16x8*)&z_s[(kg * 64 + r) * 8] = hv;
        }
        zsq_part[kq][r] = sq;
    }
    __syncthreads();

    const int m = tid & 31;        // code-lane within 32-tile
    const int h = (tid >> 5) & 1;  // k-half
    const int w = tid >> 6;        // wave id 0..7

    int bk[32];
    #pragma unroll
    for (int s = 0; s < 32; ++s) bk[s] = 0x7FFFFFFF;

    // ---- Phase B: MFMA + running packed argmin ----
    for (int c = 0; c < 4; ++c) {
        const int cb = w * 128 + c * 32;
        const int code = cb + m;
        const f16* ebp = emb_h + (size_t)h * 8192 + (size_t)code * 8;

        f32x16 acc0, acc1;
        #pragma unroll
        for (int i = 0; i < 16; ++i) { acc0[i] = 0.f; acc1[i] = 0.f; }

        #pragma unroll 4
        for (int ks = 0; ks < 16; ++ks) {
            const f16* za = z_s + (2 * ks + h) * 512 + m * 8;
            f16x8 a0 = *(const f16x8*)(za);          // rows m
            f16x8 a1 = *(const f16x8*)(za + 256);    // rows m+32
            f16x8 b0 = *(const f16x8*)(ebp + (size_t)ks * 16384);
            acc0 = __builtin_amdgcn_mfma_f32_32x32x16_f16(a0, b0, acc0, 0, 0, 0);
            acc1 = __builtin_amdgcn_mfma_f32_32x32x16_f16(a1, b0, acc1, 0, 0, 0);
        }

        const float cs = c_sq[code];
        #pragma unroll
        for (int reg = 0; reg < 16; ++reg) {
            float s0 = fmaf(-2.f, acc0[reg], cs);
            float s1 = fmaf(-2.f, acc1[reg], cs);
            int k0 = (int)(s0 * KEY_SCALE) * 1024 + code;
            int k1 = (int)(s1 * KEY_SCALE) * 1024 + code;
            bk[reg] = min(bk[reg], k0);
            bk[16 + reg] = min(bk[16 + reg], k1);
        }
    }

    // butterfly min across 32 lanes of each half
    #pragma unroll
    for (int s = 0; s < 32; ++s) {
        int k = bk[s];
        #pragma unroll
        for (int d = 16; d >= 1; d >>= 1) k = min(k, __shfl_xor(k, d));
        bk[s] = k;
    }
    if (m == 0) {
        #pragma unroll
        for (int s = 0; s < 32; ++s) {
            int rt = s >> 4, reg = s & 15;
            int row = rt * 32 + (reg & 3) + 8 * (reg >> 2) + 4 * h;
            bl_key[w][row] = bk[s];
        }
    }
    __syncthreads();

    // combine 8 waves -> idx, hist, loss-from-score
    if (tid < 64) {
        int k = bl_key[0][tid];
        #pragma unroll
        for (int w2 = 1; w2 < 8; ++w2) k = min(k, bl_key[w2][tid]);
        int i = k & 1023;               // low 10 bits = code (two's complement safe)
        idx_s[tid] = i;
        atomicAdd(&counts[i], 1);
        float zq = 0.f;
        #pragma unroll
        for (int p = 0; p < 8; ++p) zq += zsq_part[p][tid];
        float lr = (float)(k >> 10) * KEY_INV + zq;  // score_min + ||z||^2
        #pragma unroll
        for (int off = 32; off > 0; off >>= 1) lr += __shfl_down(lr, off);
        if (tid == 0) atomicAdd(loss_acc, lr);
    }
    __syncthreads();

    // ---- Phase C1: Qh[r][c] = emb[idx[r]][c] fp32, stride 260 ----
    {
        int r = tid & 63;
        int part = tid >> 6;  // 0..7 -> 32 channels each
        const float* ep = emb + (size_t)idx_s[r] * DD + part * 32;
        float* qrow = Qh + r * 260 + part * 32;
        #pragma unroll
        for (int g = 0; g < 8; ++g)
            *(float4*)(qrow + g * 4) = *(const float4*)(ep + g * 4);
    }
    __syncthreads();

    // ---- Phase C2: coalesced channel-major writes ----
    {
        int r = tid & 63;
        const float* qr = Qh + r * 260;
        const size_t base = (size_t)b * (DD * 1024) + hw0 + r;
        #pragma unroll
        for (int g = 0; g < 8; ++g) {
            int c0 = w * 32 + g * 4;
            float4 v = *(const float4*)(qr + c0);
            out[base + (size_t)c0 * 1024] = v.x;
            out[base + (size_t)(c0 + 1) * 1024] = v.y;
            out[base + (size_t)(c0 + 2) * 1024] = v.z;
            out[base + (size_t)(c0 + 3) * 1024] = v.w;
        }
    }

    // ---- last-block finalize ----
    __syncthreads();
    if (tid == 0) {
        __threadfence();
        last_flag = (atomicAdd(done, 1u) == 511u) ? 1 : 0;
    }
    __syncthreads();
    if (last_flag) {
        __threadfence();
        float s = 0.f;
        for (int k = tid; k < KC; k += 512) {
            int cnt = atomicAdd(&counts[k], 0);
            float p = (float)cnt * (1.0f / (float)NROWS);
            s += p * logf(p + 1e-10f);
        }
        #pragma unroll
        for (int off = 32; off > 0; off >>= 1) s += __shfl_down(s, off);
        if ((tid & 63) == 0) wsum[w] = s;
        __syncthreads();
        if (tid == 0) {
            float ent = 0.f;
            #pragma unroll
            for (int p = 0; p < 8; ++p) ent += wsum[p];
            float ls = atomicAdd(loss_acc, 0.0f);
            out_tail[0] = 1.25f * ls * (1.0f / (float)NELEM);
            out_tail[1] = expf(-ent);
        }
    }
}

// ---------------------------------------------------------------------------
extern "C" void kernel_launch(void* const* d_in, const int* in_sizes, int n_in,
                              void* d_out, int out_size, void* d_ws, size_t ws_size,
                              hipStream_t stream) {
    const float* z = (const float*)d_in[0];    // (32,256,32,32)
    const float* emb = (const float*)d_in[1];  // (1024,256)
    float* out = (float*)d_out;                // 8388608 + 2

    char* wsb = (char*)d_ws;
    f16* emb_h = (f16*)wsb;
    float* c_sq = (float*)(wsb + 524288);
    int* counts = (int*)(wsb + 528384);
    float* loss_acc = (float*)(wsb + 532480);
    unsigned* done = (unsigned*)(wsb + 532484);

    hipLaunchKernelGGL(vq_prep_kernel, dim3(256), dim3(256), 0, stream,
                       emb, emb_h, c_sq, counts, loss_acc, done);
    hipLaunchKernelGGL(vq_main_kernel, dim3(512), dim3(512), 0, stream,
                       z, emb, emb_h, c_sq, counts, loss_acc, done, out, out + NELEM);
}